// Round 16
// baseline (246.469 us; speedup 1.0000x reference)
//
#include <hip/hip_runtime.h>
#include <math.h>

#define CIN 128
#define HD  96
#define SP  3136   // 56*56
#define ROW 56
#define SLAB 1568  // 28*56
#define YSTRIDE 9216   // per-(b,f1) y-partial block: 64*128 + 8*128

// ---------------- Kernel W: Wt[c][o] = Wc[o][c] (96x128 -> 128x96) ----------------
__global__ __launch_bounds__(256) void wtq_k(
    const float* __restrict__ Wc, float* __restrict__ Wt)
{
  const int idx = blockIdx.x * 256 + threadIdx.x;   // 0..12287
  if (idx >= 96 * 128) return;
  const int o = idx >> 7, c = idx & 127;            // read Wc coalesced
  Wt[c * 96 + o] = Wc[idx];
}

// ---------------- Kernel A: P[e][ci][co] = sum_c Wo[co][e*24+c]*Wp[e*24+c][ci]; obp ----------------
__global__ __launch_bounds__(256) void pe_k(
    const float* __restrict__ Wo, const float* __restrict__ Wp,
    const float* __restrict__ bp, float* __restrict__ P, float* __restrict__ obp)
{
  const int e = blockIdx.x;
  __shared__ float ws[24][128];
  const int tid = threadIdx.x;
  for (int i = tid; i < 24 * 128; i += 256)
    ws[i >> 7][i & 127] = Wp[(size_t)(e * 24 + (i >> 7)) * CIN + (i & 127)];
  __syncthreads();
  const int co = tid & 127;
  const int cig = tid >> 7;
  float wo_r[24];
  #pragma unroll
  for (int c = 0; c < 24; ++c) wo_r[c] = Wo[(size_t)co * HD + e * 24 + c];
  for (int ci = cig * 64; ci < cig * 64 + 64; ++ci) {
    float s = 0.f;
    #pragma unroll
    for (int c = 0; c < 24; ++c) s = fmaf(wo_r[c], ws[c][ci], s);
    P[((size_t)e * 128 + ci) * 128 + co] = s;
  }
  if (cig == 0) {
    float s = 0.f;
    #pragma unroll
    for (int c = 0; c < 24; ++c) s = fmaf(wo_r[c], bp[e * 24 + c], s);
    obp[e * 128 + co] = s;
  }
}

// ---------------- Kernel 1: q-only 1x1 conv — LDS-FREE: scalar W + direct coalesced x ----------------
// 512 threads = 8 waves; wave = 12 outputs (o0 wave-uniform -> s_load W);
// lane = pixel; x loaded per-lane from global (L1 broadcast across waves).
// lgkmcnt carries ONLY s_loads; x waits on vmcnt -> counters decoupled.
__global__ __launch_bounds__(512) void q_conv(
    const float* __restrict__ x, const float* __restrict__ Wt,
    const float* __restrict__ bc, float* __restrict__ qbuf)
{
  const int st = blockIdx.x % 49;
  const int b  = blockIdx.x / 49;
  const int tid  = threadIdx.x;
  const int lane = tid & 63;
  const int o0   = __builtin_amdgcn_readfirstlane(tid >> 6) * 12;   // wave-uniform
  const float* xg = x + (size_t)b * CIN * SP + st * 64 + lane;

  float acc[12];
  #pragma unroll
  for (int i = 0; i < 12; ++i) acc[i] = 0.f;

  for (int c0 = 0; c0 < CIN; c0 += 8) {
    float xv[8];
    #pragma unroll
    for (int u = 0; u < 8; ++u) xv[u] = xg[(size_t)(c0 + u) * SP];   // 8 outstanding
    #pragma unroll
    for (int u = 0; u < 8; ++u) asm volatile("" : "+v"(xv[u]));      // anti-fission pin
    #pragma unroll
    for (int u = 0; u < 8; ++u) {
      const float* wr = Wt + (size_t)(c0 + u) * 96 + o0;             // uniform -> s_load
      const float4 w0 = *reinterpret_cast<const float4*>(wr + 0);
      const float4 w1 = *reinterpret_cast<const float4*>(wr + 4);
      const float4 w2 = *reinterpret_cast<const float4*>(wr + 8);
      acc[0]  = fmaf(w0.x, xv[u], acc[0]);
      acc[1]  = fmaf(w0.y, xv[u], acc[1]);
      acc[2]  = fmaf(w0.z, xv[u], acc[2]);
      acc[3]  = fmaf(w0.w, xv[u], acc[3]);
      acc[4]  = fmaf(w1.x, xv[u], acc[4]);
      acc[5]  = fmaf(w1.y, xv[u], acc[5]);
      acc[6]  = fmaf(w1.z, xv[u], acc[6]);
      acc[7]  = fmaf(w1.w, xv[u], acc[7]);
      acc[8]  = fmaf(w2.x, xv[u], acc[8]);
      acc[9]  = fmaf(w2.y, xv[u], acc[9]);
      acc[10] = fmaf(w2.z, xv[u], acc[10]);
      acc[11] = fmaf(w2.w, xv[u], acc[11]);
    }
  }
  #pragma unroll
  for (int i = 0; i < 12; ++i) {
    const int o = o0 + i;
    qbuf[((size_t)b*96 + o) * SP + st*64 + lane] = acc[i] + bc[o];
  }
}

// ---------------- Kernel 2: clustering per (b,e,f1); exports s (ch0), g (ch1), dn (ch2) ----------------
__global__ __launch_bounds__(512, 4) void cluster_k(
    float* qbuf, const float* __restrict__ alpha_p, const float* __restrict__ beta_p)
{
  const int blk = blockIdx.x;              // (b*4+e)*2 + f1
  const int f1  = blk & 1;
  const int be  = blk >> 1;
  const size_t base = (size_t)be * 24 * SP + (size_t)(f1 * 28) * ROW;
  float* qp = qbuf + base;

  __shared__ double cnd[24][8];
  __shared__ float  sbest[SLAB];
  __shared__ unsigned char ibest[SLAB];
  __shared__ float dnl[8];

  const int tid  = threadIdx.x;
  const int wid  = tid >> 6;
  const int lane = tid & 63;

  for (int c = wid; c < 24; c += 8) {
    const float* src = qp + (size_t)c * SP;
    double b0=0,b1=0,b2=0,b3=0,b4=0,b5=0,b6=0,b7=0;
    for (int n = lane; n < SLAB; n += 64) {
      const int w = n / 56, h = n - w * 56;
      const int hf = (h >= 28) ? (h - 28) : h;
      const int g  = ((h >= 28) ? 4 : 0) + ((w >= 14) ? 2 : 0) + ((hf >= 14) ? 1 : 0);
      const double val = (double)src[n];
      b0 += (g==0)?val:0.0; b1 += (g==1)?val:0.0;
      b2 += (g==2)?val:0.0; b3 += (g==3)?val:0.0;
      b4 += (g==4)?val:0.0; b5 += (g==5)?val:0.0;
      b6 += (g==6)?val:0.0; b7 += (g==7)?val:0.0;
    }
    #pragma unroll
    for (int m = 32; m >= 1; m >>= 1) {
      b0 += __shfl_xor(b0,m); b1 += __shfl_xor(b1,m);
      b2 += __shfl_xor(b2,m); b3 += __shfl_xor(b3,m);
      b4 += __shfl_xor(b4,m); b5 += __shfl_xor(b5,m);
      b6 += __shfl_xor(b6,m); b7 += __shfl_xor(b7,m);
    }
    if (lane == 0) {
      cnd[c][0]=b0*(1.0/196.0); cnd[c][1]=b1*(1.0/196.0);
      cnd[c][2]=b2*(1.0/196.0); cnd[c][3]=b3*(1.0/196.0);
      cnd[c][4]=b4*(1.0/196.0); cnd[c][5]=b5*(1.0/196.0);
      cnd[c][6]=b6*(1.0/196.0); cnd[c][7]=b7*(1.0/196.0);
    }
  }
  __syncthreads();
  if (tid < 8) {
    double s = 0.0;
    #pragma unroll
    for (int c = 0; c < 24; ++c) { double t = cnd[c][tid]; s += t * t; }
    const double inv = 1.0 / fmax(sqrt(s), 1e-12);
    #pragma unroll
    for (int c = 0; c < 24; ++c) cnd[c][tid] *= inv;
  }
  __syncthreads();

  const double alpha = (double)alpha_p[0];
  const double beta  = (double)beta_p[0];

  for (int n0 = tid; n0 < SLAB; n0 += 512) {
    const int h  = n0 % 56;
    const int gb = (h >= 28) ? 4 : 0;
    double z0=0,z1=0,z2=0,z3=0,nrm=0;
    for (int c = 0; c < 24; ++c) {
      const double qv = (double)qp[(size_t)c * SP + n0];
      z0 += cnd[c][gb+0]*qv; z1 += cnd[c][gb+1]*qv;
      z2 += cnd[c][gb+2]*qv; z3 += cnd[c][gb+3]*qv;
      nrm += qv*qv;
    }
    const double inv = 1.0 / fmax(sqrt(nrm), 1e-12);
    const double v0 = beta + alpha * (z0 * inv);
    const double v1 = beta + alpha * (z1 * inv);
    const double v2 = beta + alpha * (z2 * inv);
    const double v3 = beta + alpha * (z3 * inv);
    double zb = v0; int bi = 0;
    if (v1 > zb) { zb = v1; bi = 1; }
    if (v2 > zb) { zb = v2; bi = 2; }
    if (v3 > zb) { zb = v3; bi = 3; }
    sbest[n0] = (float)(1.0 / (1.0 + exp(-zb)));
    ibest[n0] = (unsigned char)(gb + bi);
  }
  __syncthreads();

  if (wid < 8) {
    float dn = 0.f;
    for (int ch = 0; ch < 25; ++ch) {
      const int n = ch * 64 + lane;
      const bool p = (n < SLAB) && (ibest[n] == (unsigned char)wid);
      dn += p ? sbest[n] : 0.f;
    }
    #pragma unroll
    for (int m = 32; m >= 1; m >>= 1) dn += __shfl_xor(dn, m);
    if (lane == 0) dnl[wid] = dn;
  }
  __syncthreads();

  for (int i = tid; i < SLAB; i += 512) {
    qp[i] = sbest[i];
    reinterpret_cast<unsigned int*>(qp + SP)[i] = (unsigned int)ibest[i];
  }
  if (tid < 8) qp[2 * (size_t)SP + tid] = dnl[tid];
}

// ---------------- Kernel 3: seg sums, transposed (lane=channel, pixel wave-uniform) ----------------
__global__ __launch_bounds__(256, 2) void seg_k(
    float* qbuf, const float* __restrict__ x)
{
  const int bid = blockIdx.x;            // ((b*2+f1)*2+f2)*2+wh
  const int wh  = bid & 1;
  const int f2  = (bid >> 1) & 1;
  const int f1  = (bid >> 2) & 1;
  const int b   = bid >> 3;

  __shared__ float4 sq_l[392];
  __shared__ unsigned int gq_l[392];
  __shared__ float xT[56][130];
  __shared__ float ysum[16][128];
  __shared__ float xps[2][128];

  const int tid = threadIdx.x;
  const int c   = tid & 127;
  const int pg  = tid >> 7;

  for (int n = tid; n < 392; n += 256) {
    const int r = n / 28, hc = n - r * 28;
    const int n_slab = (wh * 14 + r) * 56 + f2 * 28 + hc;
    float4 s4; unsigned int gp = 0;
    #pragma unroll
    for (int e = 0; e < 4; ++e) {
      const float* qp = qbuf + (size_t)(b*4 + e) * 24 * SP + (size_t)(f1*28) * ROW;
      const float sv = qp[n_slab];
      const unsigned int gv = reinterpret_cast<const unsigned int*>(qp + SP)[n_slab];
      if (e==0) s4.x = sv; else if (e==1) s4.y = sv;
      else if (e==2) s4.z = sv; else s4.w = sv;
      gp |= (gv & 3u) << (2*e);
    }
    sq_l[n] = s4; gq_l[n] = gp;
  }

  float sa[16];
  #pragma unroll
  for (int i = 0; i < 16; ++i) sa[i] = 0.f;
  float xp0 = 0.f, xp1 = 0.f;

  const float* xb = x + (size_t)b * CIN * SP;
  const int rowbase = f1*28 + wh*14;

  for (int ch = 0; ch < 7; ++ch) {
    __syncthreads();
    #pragma unroll
    for (int k = 0; k < 7; ++k) {
      const int slot = tid + k * 256;
      const int c2 = slot / 14, p4 = slot - c2 * 14;
      const int rr = p4 / 7, col4 = p4 - rr * 7;
      const int w = rowbase + ch*2 + rr;
      const float4 v = *reinterpret_cast<const float4*>(
          xb + (size_t)c2 * SP + (size_t)w * ROW + f2*28 + col4*4);
      const int pxl = rr * 28 + col4 * 4;
      xT[pxl+0][c2] = v.x; xT[pxl+1][c2] = v.y;
      xT[pxl+2][c2] = v.z; xT[pxl+3][c2] = v.w;
    }
    __syncthreads();
    for (int i = 0; i < 28; ++i) {
      const int pxl = 2*i + pg;
      const int n   = ch*56 + pxl;
      const float4 s4 = sq_l[n];
      const int gp = __builtin_amdgcn_readfirstlane((int)gq_l[n]);
      const float xv = xT[pxl][c];
      {
        const int k = gp & 3;
        if      (k == 0) sa[0]  += s4.x * xv;
        else if (k == 1) sa[1]  += s4.x * xv;
        else if (k == 2) sa[2]  += s4.x * xv;
        else             sa[3]  += s4.x * xv;
      }
      {
        const int k = (gp >> 2) & 3;
        if      (k == 0) sa[4]  += s4.y * xv;
        else if (k == 1) sa[5]  += s4.y * xv;
        else if (k == 2) sa[6]  += s4.y * xv;
        else             sa[7]  += s4.y * xv;
      }
      {
        const int k = (gp >> 4) & 3;
        if      (k == 0) sa[8]  += s4.z * xv;
        else if (k == 1) sa[9]  += s4.z * xv;
        else if (k == 2) sa[10] += s4.z * xv;
        else             sa[11] += s4.z * xv;
      }
      {
        const int k = (gp >> 6) & 3;
        if      (k == 0) sa[12] += s4.w * xv;
        else if (k == 1) sa[13] += s4.w * xv;
        else if (k == 2) sa[14] += s4.w * xv;
        else             sa[15] += s4.w * xv;
      }
      const int hc = (pxl >= 28) ? (pxl - 28) : pxl;
      if (hc >= 14) xp1 += xv; else xp0 += xv;
    }
  }

  __syncthreads();
  if (pg == 0) {
    #pragma unroll
    for (int k = 0; k < 16; ++k) ysum[k][c] = sa[k];
    xps[0][c] = xp0; xps[1][c] = xp1;
  }
  __syncthreads();
  if (pg == 1) {
    #pragma unroll
    for (int k = 0; k < 16; ++k) ysum[k][c] += sa[k];
    xps[0][c] += xp0; xps[1][c] += xp1;
  }
  __syncthreads();

  float* ybase = qbuf + ((size_t)b*96 + 9) * SP + (size_t)f1 * YSTRIDE;
  for (int i = tid; i < 16*128; i += 256) {
    const int row = i >> 7, cc = i & 127;
    ybase[((wh*2 + f2)*16 + row)*128 + cc] = ysum[row][cc];
  }
  {
    const int hb = tid >> 7, cc = tid & 127;
    ybase[64*128 + (f2*4 + wh*2 + hb)*128 + cc] = xps[hb][cc];
  }
}

// ---------------- Kernel 4: proj[eg][co] = P_e y_eg + obp_e per (b,f1); combines y-partials ----------------
__global__ __launch_bounds__(256) void proj_k(
    float* qbuf, const float* __restrict__ P, const float* __restrict__ obp)
{
  const int bid = blockIdx.x;       // b*2 + f1
  const int b = bid >> 1, f1 = bid & 1;
  __shared__ float ylds[32][128];
  __shared__ float invs[32];
  const int tid = threadIdx.x;

  if (tid < 32) {
    const int e = tid >> 3, g = tid & 7;
    const float* dnp = qbuf + ((size_t)(b*4 + e) * 24 + 2) * SP + (size_t)(f1*28) * ROW;
    invs[tid] = 1.f / (dnp[g] + 1.f);
  }
  __syncthreads();

  const float* yp = qbuf + ((size_t)b*96 + 9) * SP + (size_t)f1 * YSTRIDE;
  for (int i = tid; i < 32*128; i += 256) {
    const int eg = i >> 7, cc = i & 127;
    const int e = eg >> 3, g = eg & 7, ff2 = g >> 2, m = g & 3;
    const float v = yp[((0 + ff2)*16 + e*4 + m)*128 + cc]
                  + yp[((2 + ff2)*16 + e*4 + m)*128 + cc]
                  + yp[64*128 + g*128 + cc] * (1.f/196.f);
    ylds[eg][cc] = v * invs[eg];
  }
  __syncthreads();

  const int co = tid & 127;
  const int e0 = (tid >> 7) * 2;
  float a0[8], a1[8];
  const float o0 = obp[e0 * 128 + co], o1 = obp[(e0 + 1) * 128 + co];
  #pragma unroll
  for (int g = 0; g < 8; ++g) { a0[g] = o0; a1[g] = o1; }
  for (int ci = 0; ci < 128; ++ci) {
    const float p0 = P[((size_t)e0 * 128 + ci) * 128 + co];
    const float p1 = P[((size_t)(e0 + 1) * 128 + ci) * 128 + co];
    #pragma unroll
    for (int g = 0; g < 8; ++g) {
      a0[g] = fmaf(p0, ylds[e0 * 8 + g][ci], a0[g]);
      a1[g] = fmaf(p1, ylds[(e0 + 1) * 8 + g][ci], a1[g]);
    }
  }
  float* pout = qbuf + ((size_t)b * 96 + 3 + f1 * 3) * SP;
  #pragma unroll
  for (int g = 0; g < 8; ++g) {
    pout[(e0 * 8 + g) * 128 + co]       = a0[g];
    pout[((e0 + 1) * 8 + g) * 128 + co] = a1[g];
  }
}

// ---------------- Kernel 5: output via proj lookup (unchanged) ----------------
__global__ __launch_bounds__(256) void out_k(
    const float* __restrict__ qbuf, const float* __restrict__ bo,
    float* __restrict__ out)
{
  const int bid = blockIdx.x;           // (b*2+f1)*14 + rp
  const int b   = bid / 28;
  const int rem = bid % 28;
  const int f1  = rem / 14;
  const int rp  = rem % 14;
  const int n0  = rp * 112;

  __shared__ float  proj_l[4096];
  __shared__ float4 s_l4[112];
  __shared__ unsigned int g_l[112];
  __shared__ float  out_l[56 * 132];

  const int tid = threadIdx.x;

  {
    const float4* pg = reinterpret_cast<const float4*>(
        qbuf + ((size_t)b * 96 + 3 + f1*3) * SP);
    float4* pl = reinterpret_cast<float4*>(proj_l);
    #pragma unroll
    for (int r = 0; r < 4; ++r) pl[tid + r * 256] = pg[tid + r * 256];
  }
  for (int i = tid; i < 112; i += 256) {
    float4 sv; unsigned int gp = 0;
    #pragma unroll
    for (int e = 0; e < 4; ++e) {
      const float* sp = qbuf + ((size_t)(b*4 + e) * 24) * SP + (size_t)(f1*28) * ROW;
      const float sval = sp[n0 + i];
      const unsigned int gv = reinterpret_cast<const unsigned int*>(sp + SP)[n0 + i];
      if (e == 0) sv.x = sval; else if (e == 1) sv.y = sval;
      else if (e == 2) sv.z = sval; else sv.w = sval;
      gp |= (gv & 7u) << (8 * e);
    }
    s_l4[i] = sv; g_l[i] = gp;
  }
  __syncthreads();

  const int cq  = tid & 31;
  const int sub = tid >> 5;
  const float4 bo4 = *reinterpret_cast<const float4*>(bo + cq * 4);
  const float4* pl4 = reinterpret_cast<const float4*>(proj_l);

  for (int chunk = 0; chunk < 2; ++chunk) {
    const int pbase = chunk * 56;
    #pragma unroll
    for (int i = 0; i < 7; ++i) {
      const int pxl = sub * 7 + i;
      const int px  = pbase + pxl;
      const float4 sv = s_l4[px];
      const unsigned int gp = g_l[px];
      float4 acc = bo4;
      {
        const float4 p = pl4[(0*8 + (gp        & 7u)) * 32 + cq];
        acc.x = fmaf(sv.x, p.x, acc.x); acc.y = fmaf(sv.x, p.y, acc.y);
        acc.z = fmaf(sv.x, p.z, acc.z); acc.w = fmaf(sv.x, p.w, acc.w);
      }
      {
        const float4 p = pl4[(1*8 + ((gp >> 8) & 7u)) * 32 + cq];
        acc.x = fmaf(sv.y, p.x, acc.x); acc.y = fmaf(sv.y, p.y, acc.y);
        acc.z = fmaf(sv.y, p.z, acc.z); acc.w = fmaf(sv.y, p.w, acc.w);
      }
      {
        const float4 p = pl4[(2*8 + ((gp >> 16) & 7u)) * 32 + cq];
        acc.x = fmaf(sv.z, p.x, acc.x); acc.y = fmaf(sv.z, p.y, acc.y);
        acc.z = fmaf(sv.z, p.z, acc.z); acc.w = fmaf(sv.z, p.w, acc.w);
      }
      {
        const float4 p = pl4[(3*8 + ((gp >> 24) & 7u)) * 32 + cq];
        acc.x = fmaf(sv.w, p.x, acc.x); acc.y = fmaf(sv.w, p.y, acc.y);
        acc.z = fmaf(sv.w, p.z, acc.z); acc.w = fmaf(sv.w, p.w, acc.w);
      }
      *reinterpret_cast<float4*>(&out_l[pxl * 132 + cq * 4]) = acc;
    }
    __syncthreads();
    for (int t = tid; t < 128 * 56; t += 256) {
      const int co = t / 56, pxl = t - co * 56;
      out[((size_t)b * 128 + co) * SP + (size_t)f1 * SLAB + n0 + pbase + pxl] =
          out_l[pxl * 132 + co];
    }
    __syncthreads();
  }
}

extern "C" void kernel_launch(void* const* d_in, const int* in_sizes, int n_in,
                              void* d_out, int out_size, void* d_ws, size_t ws_size,
                              hipStream_t stream) {
  const float* x  = (const float*)d_in[0];
  const float* Wc = (const float*)d_in[1];
  const float* bc = (const float*)d_in[2];
  const float* Wp = (const float*)d_in[3];
  const float* bp = (const float*)d_in[4];
  const float* sa = (const float*)d_in[5];
  const float* sb = (const float*)d_in[6];
  const float* Wo = (const float*)d_in[7];
  const float* bo = (const float*)d_in[8];
  float* out  = (float*)d_out;
  float* qbuf = (float*)d_ws;        // 77.1 MB; exports/y/proj reuse dead q channels
  float* Pbuf = out;                 // P: [0, 65536)
  float* obpb = out + 65536;         // obp: [65536, 66048)
  float* Wtq  = out + 66048;         // Wt: [66048, 78336) — all consumed before out_k

  wtq_k    <<<dim3(48),      dim3(256), 0, stream>>>(Wc, Wtq);
  pe_k     <<<dim3(4),       dim3(256), 0, stream>>>(Wo, Wp, bp, Pbuf, obpb);
  q_conv   <<<dim3(64 * 49), dim3(512), 0, stream>>>(x, Wtq, bc, qbuf);
  cluster_k<<<dim3(512),     dim3(512), 0, stream>>>(qbuf, sa, sb);
  seg_k    <<<dim3(512),     dim3(256), 0, stream>>>(qbuf, x);
  proj_k   <<<dim3(128),     dim3(256), 0, stream>>>(qbuf, Pbuf, obpb);
  out_k    <<<dim3(1792),    dim3(256), 0, stream>>>(qbuf, bo, out);
}

// Round 17
// 224.519 us; speedup vs baseline: 1.0978x; 1.0978x over previous
//
#include <hip/hip_runtime.h>
#include <math.h>

#define CIN 128
#define HD  96
#define SP  3136   // 56*56
#define ROW 56
#define SLAB 1568  // 28*56
#define YSTRIDE 9216   // per-(b,f1) y-partial block: 64*128 + 8*128

// ---------------- Kernel W: Wt[c][o] = Wc[o][c] (96x128 -> 128x96) ----------------
__global__ __launch_bounds__(256) void wtq_k(
    const float* __restrict__ Wc, float* __restrict__ Wt)
{
  const int idx = blockIdx.x * 256 + threadIdx.x;   // 0..12287
  if (idx >= 96 * 128) return;
  const int o = idx >> 7, c = idx & 127;            // read Wc coalesced
  Wt[c * 96 + o] = Wc[idx];
}

// ---------------- Kernel A: P[e][ci][co] = sum_c Wo[co][e*24+c]*Wp[e*24+c][ci]; obp ----------------
__global__ __launch_bounds__(256) void pe_k(
    const float* __restrict__ Wo, const float* __restrict__ Wp,
    const float* __restrict__ bp, float* __restrict__ P, float* __restrict__ obp)
{
  const int e = blockIdx.x;
  __shared__ float ws[24][128];
  const int tid = threadIdx.x;
  for (int i = tid; i < 24 * 128; i += 256)
    ws[i >> 7][i & 127] = Wp[(size_t)(e * 24 + (i >> 7)) * CIN + (i & 127)];
  __syncthreads();
  const int co = tid & 127;
  const int cig = tid >> 7;
  float wo_r[24];
  #pragma unroll
  for (int c = 0; c < 24; ++c) wo_r[c] = Wo[(size_t)co * HD + e * 24 + c];
  for (int ci = cig * 64; ci < cig * 64 + 64; ++ci) {
    float s = 0.f;
    #pragma unroll
    for (int c = 0; c < 24; ++c) s = fmaf(wo_r[c], ws[c][ci], s);
    P[((size_t)e * 128 + ci) * 128 + co] = s;
  }
  if (cig == 0) {
    float s = 0.f;
    #pragma unroll
    for (int c = 0; c < 24; ++c) s = fmaf(wo_r[c], bp[e * 24 + c], s);
    obp[e * 128 + co] = s;
  }
}

// ---------------- Kernel 1: q-only 1x1 conv — whole-x-in-LDS, scalar W chunked by 4cc ----------------
// 512 threads = 8 waves; wave = 12 outputs (o0 wave-uniform -> s_load W);
// lane = pixel; xs[128][64] staged ONCE (no barriers in main loop).
__global__ __launch_bounds__(512) void q_conv(
    const float* __restrict__ x, const float* __restrict__ Wt,
    const float* __restrict__ bc, float* __restrict__ qbuf)
{
  const int st = blockIdx.x % 49;
  const int b  = blockIdx.x / 49;
  const float* xb = x + (size_t)b * CIN * SP + st * 64;

  __shared__ float xs[128][64];   // 32 KB — all channels for this 64-px strip

  const int tid  = threadIdx.x;
  const int lane = tid & 63;
  const int o0   = __builtin_amdgcn_readfirstlane(tid >> 6) * 12;   // wave-uniform

  // stage all 128 channels: 2048 float4 tasks, 4 per thread, coalesced
  #pragma unroll
  for (int r = 0; r < 4; ++r) {
    const int i = tid + r * 512;
    const int cc = i >> 4, s4 = i & 15;
    float4 v = *reinterpret_cast<const float4*>(xb + (size_t)cc * SP + s4 * 4);
    *reinterpret_cast<float4*>(&xs[cc][s4 * 4]) = v;
  }
  __syncthreads();

  float acc[12];
  #pragma unroll
  for (int i = 0; i < 12; ++i) acc[i] = 0.f;

  #pragma unroll 4
  for (int c = 0; c < CIN; ++c) {
    const float* wr = Wt + (size_t)c * 96 + o0;            // uniform -> s_load_dwordx4
    const float4 w0 = *reinterpret_cast<const float4*>(wr + 0);
    const float4 w1 = *reinterpret_cast<const float4*>(wr + 4);
    const float4 w2 = *reinterpret_cast<const float4*>(wr + 8);
    const float xv = xs[c][lane];                          // ds_read_b32, 2-way free
    acc[0]  = fmaf(w0.x, xv, acc[0]);
    acc[1]  = fmaf(w0.y, xv, acc[1]);
    acc[2]  = fmaf(w0.z, xv, acc[2]);
    acc[3]  = fmaf(w0.w, xv, acc[3]);
    acc[4]  = fmaf(w1.x, xv, acc[4]);
    acc[5]  = fmaf(w1.y, xv, acc[5]);
    acc[6]  = fmaf(w1.z, xv, acc[6]);
    acc[7]  = fmaf(w1.w, xv, acc[7]);
    acc[8]  = fmaf(w2.x, xv, acc[8]);
    acc[9]  = fmaf(w2.y, xv, acc[9]);
    acc[10] = fmaf(w2.z, xv, acc[10]);
    acc[11] = fmaf(w2.w, xv, acc[11]);
  }
  #pragma unroll
  for (int i = 0; i < 12; ++i) {
    const int o = o0 + i;
    qbuf[((size_t)b * 96 + o) * SP + st * 64 + lane] = acc[i] + bc[o];
  }
}

// ---------------- Kernel 2: clustering per (b,e,f1); exports s (ch0), g (ch1), dn (ch2) ----------------
__global__ __launch_bounds__(512, 4) void cluster_k(
    float* qbuf, const float* __restrict__ alpha_p, const float* __restrict__ beta_p)
{
  const int blk = blockIdx.x;              // (b*4+e)*2 + f1
  const int f1  = blk & 1;
  const int be  = blk >> 1;
  const size_t base = (size_t)be * 24 * SP + (size_t)(f1 * 28) * ROW;
  float* qp = qbuf + base;

  __shared__ double cnd[24][8];
  __shared__ float  sbest[SLAB];
  __shared__ unsigned char ibest[SLAB];
  __shared__ float dnl[8];

  const int tid  = threadIdx.x;
  const int wid  = tid >> 6;
  const int lane = tid & 63;

  for (int c = wid; c < 24; c += 8) {
    const float* src = qp + (size_t)c * SP;
    double b0=0,b1=0,b2=0,b3=0,b4=0,b5=0,b6=0,b7=0;
    for (int n = lane; n < SLAB; n += 64) {
      const int w = n / 56, h = n - w * 56;
      const int hf = (h >= 28) ? (h - 28) : h;
      const int g  = ((h >= 28) ? 4 : 0) + ((w >= 14) ? 2 : 0) + ((hf >= 14) ? 1 : 0);
      const double val = (double)src[n];
      b0 += (g==0)?val:0.0; b1 += (g==1)?val:0.0;
      b2 += (g==2)?val:0.0; b3 += (g==3)?val:0.0;
      b4 += (g==4)?val:0.0; b5 += (g==5)?val:0.0;
      b6 += (g==6)?val:0.0; b7 += (g==7)?val:0.0;
    }
    #pragma unroll
    for (int m = 32; m >= 1; m >>= 1) {
      b0 += __shfl_xor(b0,m); b1 += __shfl_xor(b1,m);
      b2 += __shfl_xor(b2,m); b3 += __shfl_xor(b3,m);
      b4 += __shfl_xor(b4,m); b5 += __shfl_xor(b5,m);
      b6 += __shfl_xor(b6,m); b7 += __shfl_xor(b7,m);
    }
    if (lane == 0) {
      cnd[c][0]=b0*(1.0/196.0); cnd[c][1]=b1*(1.0/196.0);
      cnd[c][2]=b2*(1.0/196.0); cnd[c][3]=b3*(1.0/196.0);
      cnd[c][4]=b4*(1.0/196.0); cnd[c][5]=b5*(1.0/196.0);
      cnd[c][6]=b6*(1.0/196.0); cnd[c][7]=b7*(1.0/196.0);
    }
  }
  __syncthreads();
  if (tid < 8) {
    double s = 0.0;
    #pragma unroll
    for (int c = 0; c < 24; ++c) { double t = cnd[c][tid]; s += t * t; }
    const double inv = 1.0 / fmax(sqrt(s), 1e-12);
    #pragma unroll
    for (int c = 0; c < 24; ++c) cnd[c][tid] *= inv;
  }
  __syncthreads();

  const double alpha = (double)alpha_p[0];
  const double beta  = (double)beta_p[0];

  for (int n0 = tid; n0 < SLAB; n0 += 512) {
    const int h  = n0 % 56;
    const int gb = (h >= 28) ? 4 : 0;
    double z0=0,z1=0,z2=0,z3=0,nrm=0;
    for (int c = 0; c < 24; ++c) {
      const double qv = (double)qp[(size_t)c * SP + n0];
      z0 += cnd[c][gb+0]*qv; z1 += cnd[c][gb+1]*qv;
      z2 += cnd[c][gb+2]*qv; z3 += cnd[c][gb+3]*qv;
      nrm += qv*qv;
    }
    const double inv = 1.0 / fmax(sqrt(nrm), 1e-12);
    const double v0 = beta + alpha * (z0 * inv);
    const double v1 = beta + alpha * (z1 * inv);
    const double v2 = beta + alpha * (z2 * inv);
    const double v3 = beta + alpha * (z3 * inv);
    double zb = v0; int bi = 0;
    if (v1 > zb) { zb = v1; bi = 1; }
    if (v2 > zb) { zb = v2; bi = 2; }
    if (v3 > zb) { zb = v3; bi = 3; }
    sbest[n0] = (float)(1.0 / (1.0 + exp(-zb)));
    ibest[n0] = (unsigned char)(gb + bi);
  }
  __syncthreads();

  if (wid < 8) {
    float dn = 0.f;
    for (int ch = 0; ch < 25; ++ch) {
      const int n = ch * 64 + lane;
      const bool p = (n < SLAB) && (ibest[n] == (unsigned char)wid);
      dn += p ? sbest[n] : 0.f;
    }
    #pragma unroll
    for (int m = 32; m >= 1; m >>= 1) dn += __shfl_xor(dn, m);
    if (lane == 0) dnl[wid] = dn;
  }
  __syncthreads();

  for (int i = tid; i < SLAB; i += 512) {
    qp[i] = sbest[i];
    reinterpret_cast<unsigned int*>(qp + SP)[i] = (unsigned int)ibest[i];
  }
  if (tid < 8) qp[2 * (size_t)SP + tid] = dnl[tid];
}

// ---------------- Kernel 3: seg sums, transposed (lane=channel, pixel wave-uniform) ----------------
__global__ __launch_bounds__(256, 2) void seg_k(
    float* qbuf, const float* __restrict__ x)
{
  const int bid = blockIdx.x;            // ((b*2+f1)*2+f2)*2+wh
  const int wh  = bid & 1;
  const int f2  = (bid >> 1) & 1;
  const int f1  = (bid >> 2) & 1;
  const int b   = bid >> 3;

  __shared__ float4 sq_l[392];
  __shared__ unsigned int gq_l[392];
  __shared__ float xT[56][130];
  __shared__ float ysum[16][128];
  __shared__ float xps[2][128];

  const int tid = threadIdx.x;
  const int c   = tid & 127;
  const int pg  = tid >> 7;

  for (int n = tid; n < 392; n += 256) {
    const int r = n / 28, hc = n - r * 28;
    const int n_slab = (wh * 14 + r) * 56 + f2 * 28 + hc;
    float4 s4; unsigned int gp = 0;
    #pragma unroll
    for (int e = 0; e < 4; ++e) {
      const float* qp = qbuf + (size_t)(b*4 + e) * 24 * SP + (size_t)(f1*28) * ROW;
      const float sv = qp[n_slab];
      const unsigned int gv = reinterpret_cast<const unsigned int*>(qp + SP)[n_slab];
      if (e==0) s4.x = sv; else if (e==1) s4.y = sv;
      else if (e==2) s4.z = sv; else s4.w = sv;
      gp |= (gv & 3u) << (2*e);
    }
    sq_l[n] = s4; gq_l[n] = gp;
  }

  float sa[16];
  #pragma unroll
  for (int i = 0; i < 16; ++i) sa[i] = 0.f;
  float xp0 = 0.f, xp1 = 0.f;

  const float* xb = x + (size_t)b * CIN * SP;
  const int rowbase = f1*28 + wh*14;

  for (int ch = 0; ch < 7; ++ch) {
    __syncthreads();
    #pragma unroll
    for (int k = 0; k < 7; ++k) {
      const int slot = tid + k * 256;
      const int c2 = slot / 14, p4 = slot - c2 * 14;
      const int rr = p4 / 7, col4 = p4 - rr * 7;
      const int w = rowbase + ch*2 + rr;
      const float4 v = *reinterpret_cast<const float4*>(
          xb + (size_t)c2 * SP + (size_t)w * ROW + f2*28 + col4*4);
      const int pxl = rr * 28 + col4 * 4;
      xT[pxl+0][c2] = v.x; xT[pxl+1][c2] = v.y;
      xT[pxl+2][c2] = v.z; xT[pxl+3][c2] = v.w;
    }
    __syncthreads();
    for (int i = 0; i < 28; ++i) {
      const int pxl = 2*i + pg;
      const int n   = ch*56 + pxl;
      const float4 s4 = sq_l[n];
      const int gp = __builtin_amdgcn_readfirstlane((int)gq_l[n]);
      const float xv = xT[pxl][c];
      {
        const int k = gp & 3;
        if      (k == 0) sa[0]  += s4.x * xv;
        else if (k == 1) sa[1]  += s4.x * xv;
        else if (k == 2) sa[2]  += s4.x * xv;
        else             sa[3]  += s4.x * xv;
      }
      {
        const int k = (gp >> 2) & 3;
        if      (k == 0) sa[4]  += s4.y * xv;
        else if (k == 1) sa[5]  += s4.y * xv;
        else if (k == 2) sa[6]  += s4.y * xv;
        else             sa[7]  += s4.y * xv;
      }
      {
        const int k = (gp >> 4) & 3;
        if      (k == 0) sa[8]  += s4.z * xv;
        else if (k == 1) sa[9]  += s4.z * xv;
        else if (k == 2) sa[10] += s4.z * xv;
        else             sa[11] += s4.z * xv;
      }
      {
        const int k = (gp >> 6) & 3;
        if      (k == 0) sa[12] += s4.w * xv;
        else if (k == 1) sa[13] += s4.w * xv;
        else if (k == 2) sa[14] += s4.w * xv;
        else             sa[15] += s4.w * xv;
      }
      const int hc = (pxl >= 28) ? (pxl - 28) : pxl;
      if (hc >= 14) xp1 += xv; else xp0 += xv;
    }
  }

  __syncthreads();
  if (pg == 0) {
    #pragma unroll
    for (int k = 0; k < 16; ++k) ysum[k][c] = sa[k];
    xps[0][c] = xp0; xps[1][c] = xp1;
  }
  __syncthreads();
  if (pg == 1) {
    #pragma unroll
    for (int k = 0; k < 16; ++k) ysum[k][c] += sa[k];
    xps[0][c] += xp0; xps[1][c] += xp1;
  }
  __syncthreads();

  float* ybase = qbuf + ((size_t)b*96 + 9) * SP + (size_t)f1 * YSTRIDE;
  for (int i = tid; i < 16*128; i += 256) {
    const int row = i >> 7, cc = i & 127;
    ybase[((wh*2 + f2)*16 + row)*128 + cc] = ysum[row][cc];
  }
  {
    const int hb = tid >> 7, cc = tid & 127;
    ybase[64*128 + (f2*4 + wh*2 + hb)*128 + cc] = xps[hb][cc];
  }
}

// ---------------- Kernel 4: proj[eg][co] = P_e y_eg + obp_e per (b,f1); combines y-partials ----------------
__global__ __launch_bounds__(256) void proj_k(
    float* qbuf, const float* __restrict__ P, const float* __restrict__ obp)
{
  const int bid = blockIdx.x;       // b*2 + f1
  const int b = bid >> 1, f1 = bid & 1;
  __shared__ float ylds[32][128];
  __shared__ float invs[32];
  const int tid = threadIdx.x;

  if (tid < 32) {
    const int e = tid >> 3, g = tid & 7;
    const float* dnp = qbuf + ((size_t)(b*4 + e) * 24 + 2) * SP + (size_t)(f1*28) * ROW;
    invs[tid] = 1.f / (dnp[g] + 1.f);
  }
  __syncthreads();

  const float* yp = qbuf + ((size_t)b*96 + 9) * SP + (size_t)f1 * YSTRIDE;
  for (int i = tid; i < 32*128; i += 256) {
    const int eg = i >> 7, cc = i & 127;
    const int e = eg >> 3, g = eg & 7, ff2 = g >> 2, m = g & 3;
    const float v = yp[((0 + ff2)*16 + e*4 + m)*128 + cc]
                  + yp[((2 + ff2)*16 + e*4 + m)*128 + cc]
                  + yp[64*128 + g*128 + cc] * (1.f/196.f);
    ylds[eg][cc] = v * invs[eg];
  }
  __syncthreads();

  const int co = tid & 127;
  const int e0 = (tid >> 7) * 2;
  float a0[8], a1[8];
  const float o0 = obp[e0 * 128 + co], o1 = obp[(e0 + 1) * 128 + co];
  #pragma unroll
  for (int g = 0; g < 8; ++g) { a0[g] = o0; a1[g] = o1; }
  for (int ci = 0; ci < 128; ++ci) {
    const float p0 = P[((size_t)e0 * 128 + ci) * 128 + co];
    const float p1 = P[((size_t)(e0 + 1) * 128 + ci) * 128 + co];
    #pragma unroll
    for (int g = 0; g < 8; ++g) {
      a0[g] = fmaf(p0, ylds[e0 * 8 + g][ci], a0[g]);
      a1[g] = fmaf(p1, ylds[(e0 + 1) * 8 + g][ci], a1[g]);
    }
  }
  float* pout = qbuf + ((size_t)b * 96 + 3 + f1 * 3) * SP;
  #pragma unroll
  for (int g = 0; g < 8; ++g) {
    pout[(e0 * 8 + g) * 128 + co]       = a0[g];
    pout[((e0 + 1) * 8 + g) * 128 + co] = a1[g];
  }
}

// ---------------- Kernel 5: output via proj lookup (unchanged) ----------------
__global__ __launch_bounds__(256) void out_k(
    const float* __restrict__ qbuf, const float* __restrict__ bo,
    float* __restrict__ out)
{
  const int bid = blockIdx.x;           // (b*2+f1)*14 + rp
  const int b   = bid / 28;
  const int rem = bid % 28;
  const int f1  = rem / 14;
  const int rp  = rem % 14;
  const int n0  = rp * 112;

  __shared__ float  proj_l[4096];
  __shared__ float4 s_l4[112];
  __shared__ unsigned int g_l[112];
  __shared__ float  out_l[56 * 132];

  const int tid = threadIdx.x;

  {
    const float4* pg = reinterpret_cast<const float4*>(
        qbuf + ((size_t)b * 96 + 3 + f1*3) * SP);
    float4* pl = reinterpret_cast<float4*>(proj_l);
    #pragma unroll
    for (int r = 0; r < 4; ++r) pl[tid + r * 256] = pg[tid + r * 256];
  }
  for (int i = tid; i < 112; i += 256) {
    float4 sv; unsigned int gp = 0;
    #pragma unroll
    for (int e = 0; e < 4; ++e) {
      const float* sp = qbuf + ((size_t)(b*4 + e) * 24) * SP + (size_t)(f1*28) * ROW;
      const float sval = sp[n0 + i];
      const unsigned int gv = reinterpret_cast<const unsigned int*>(sp + SP)[n0 + i];
      if (e == 0) sv.x = sval; else if (e == 1) sv.y = sval;
      else if (e == 2) sv.z = sval; else sv.w = sval;
      gp |= (gv & 7u) << (8 * e);
    }
    s_l4[i] = sv; g_l[i] = gp;
  }
  __syncthreads();

  const int cq  = tid & 31;
  const int sub = tid >> 5;
  const float4 bo4 = *reinterpret_cast<const float4*>(bo + cq * 4);
  const float4* pl4 = reinterpret_cast<const float4*>(proj_l);

  for (int chunk = 0; chunk < 2; ++chunk) {
    const int pbase = chunk * 56;
    #pragma unroll
    for (int i = 0; i < 7; ++i) {
      const int pxl = sub * 7 + i;
      const int px  = pbase + pxl;
      const float4 sv = s_l4[px];
      const unsigned int gp = g_l[px];
      float4 acc = bo4;
      {
        const float4 p = pl4[(0*8 + (gp        & 7u)) * 32 + cq];
        acc.x = fmaf(sv.x, p.x, acc.x); acc.y = fmaf(sv.x, p.y, acc.y);
        acc.z = fmaf(sv.x, p.z, acc.z); acc.w = fmaf(sv.x, p.w, acc.w);
      }
      {
        const float4 p = pl4[(1*8 + ((gp >> 8) & 7u)) * 32 + cq];
        acc.x = fmaf(sv.y, p.x, acc.x); acc.y = fmaf(sv.y, p.y, acc.y);
        acc.z = fmaf(sv.y, p.z, acc.z); acc.w = fmaf(sv.y, p.w, acc.w);
      }
      {
        const float4 p = pl4[(2*8 + ((gp >> 16) & 7u)) * 32 + cq];
        acc.x = fmaf(sv.z, p.x, acc.x); acc.y = fmaf(sv.z, p.y, acc.y);
        acc.z = fmaf(sv.z, p.z, acc.z); acc.w = fmaf(sv.z, p.w, acc.w);
      }
      {
        const float4 p = pl4[(3*8 + ((gp >> 24) & 7u)) * 32 + cq];
        acc.x = fmaf(sv.w, p.x, acc.x); acc.y = fmaf(sv.w, p.y, acc.y);
        acc.z = fmaf(sv.w, p.z, acc.z); acc.w = fmaf(sv.w, p.w, acc.w);
      }
      *reinterpret_cast<float4*>(&out_l[pxl * 132 + cq * 4]) = acc;
    }
    __syncthreads();
    for (int t = tid; t < 128 * 56; t += 256) {
      const int co = t / 56, pxl = t - co * 56;
      out[((size_t)b * 128 + co) * SP + (size_t)f1 * SLAB + n0 + pbase + pxl] =
          out_l[pxl * 132 + co];
    }
    __syncthreads();
  }
}

extern "C" void kernel_launch(void* const* d_in, const int* in_sizes, int n_in,
                              void* d_out, int out_size, void* d_ws, size_t ws_size,
                              hipStream_t stream) {
  const float* x  = (const float*)d_in[0];
  const float* Wc = (const float*)d_in[1];
  const float* bc = (const float*)d_in[2];
  const float* Wp = (const float*)d_in[3];
  const float* bp = (const float*)d_in[4];
  const float* sa = (const float*)d_in[5];
  const float* sb = (const float*)d_in[6];
  const float* Wo = (const float*)d_in[7];
  const float* bo = (const float*)d_in[8];
  float* out  = (float*)d_out;
  float* qbuf = (float*)d_ws;        // 77.1 MB; exports/y/proj reuse dead q channels
  float* Pbuf = out;                 // P: [0, 65536)
  float* obpb = out + 65536;         // obp: [65536, 66048)
  float* Wtq  = out + 66048;         // Wt: [66048, 78336) — all consumed before out_k

  wtq_k    <<<dim3(48),      dim3(256), 0, stream>>>(Wc, Wtq);
  pe_k     <<<dim3(4),       dim3(256), 0, stream>>>(Wo, Wp, bp, Pbuf, obpb);
  q_conv   <<<dim3(64 * 49), dim3(512), 0, stream>>>(x, Wtq, bc, qbuf);
  cluster_k<<<dim3(512),     dim3(512), 0, stream>>>(qbuf, sa, sb);
  seg_k    <<<dim3(512),     dim3(256), 0, stream>>>(qbuf, x);
  proj_k   <<<dim3(128),     dim3(256), 0, stream>>>(qbuf, Pbuf, obpb);
  out_k    <<<dim3(1792),    dim3(256), 0, stream>>>(qbuf, bo, out);
}